// Round 10
// baseline (101.805 us; speedup 1.0000x reference)
//
#include <hip/hip_runtime.h>
#include <math.h>

#define BATCH 4
#define TLEN 512
#define SLEN 512
#define DM 256
#define NH 4
#define DH 64
#define BT (BATCH * TLEN)   // 2048
#define WPAD 132            // 128 k-half + 4 pad: bank=(4*o+k)%32, 2-way (free); 16B aligned

__device__ __forceinline__ float rcp_fast(float x) { return __builtin_amdgcn_rcpf(x); }

// ---- self-staging GEMM core: block = 32 rows x 64 outs; W panel (64 o x 256 k, ORIGINAL
//      row-major) staged in two 128-k halves into LDS [64][WPAD]; 8 rows/thread.
//      lane = out col; X rows wave-uniform -> s_load. acc[8] returned. ----
__device__ __forceinline__ void gemm_selfstage(const float* __restrict__ X,
                                               const float* __restrict__ W,
                                               float* __restrict__ wlds,
                                               int row0, int o0, int tid, int lane,
                                               float* acc) {
#pragma unroll
  for (int r = 0; r < 8; ++r) acc[r] = 0.f;
  const float* xb = X + (size_t)row0 * DM;          // wave-uniform
#pragma unroll 1
  for (int half = 0; half < 2; ++half) {
    __syncthreads();                                 // previous half consumed
    {
      // stage 64 rows x 128 k: 2048 float4 chunks; chunk c: row=c>>5, kq=c&31
      const float4* wsrc = (const float4*)(W + (size_t)o0 * DM + half * 128);
#pragma unroll
      for (int i = 0; i < 8; ++i) {
        int c = i * 256 + tid;
        int row = c >> 5, kq = c & 31;
        *(float4*)&wlds[row * WPAD + kq * 4] = wsrc[(size_t)row * 64 + kq];
      }
    }
    __syncthreads();
    const float* xh = xb + half * 128;
#pragma unroll 2
    for (int kk = 0; kk < 128; kk += 4) {
      float4 w = *(const float4*)&wlds[lane * WPAD + kk];
#pragma unroll
      for (int r = 0; r < 8; ++r) {
        acc[r] = fmaf(xh[r * DM + kk + 0], w.x, acc[r]);
        acc[r] = fmaf(xh[r * DM + kk + 1], w.y, acc[r]);
        acc[r] = fmaf(xh[r * DM + kk + 2], w.z, acc[r]);
        acc[r] = fmaf(xh[r * DM + kk + 3], w.w, acc[r]);
      }
    }
  }
}

// ---- kernel A: Q/K/V projections, W read directly (no transpose pre-pass).
//      EQ=[bh][t][d]; EKT=[bh][dc16][s][j4]; Vw=[bh][s/2][d][2] ----
__global__ __launch_bounds__(256) void proj_kernel(
    const float* __restrict__ q, const float* __restrict__ k, const float* __restrict__ v,
    const float* __restrict__ wq, const float* __restrict__ wk, const float* __restrict__ wv,
    float* __restrict__ EQ, float* __restrict__ EKT, float* __restrict__ Vw) {
  __shared__ float wlds[64 * WPAD];                  // 33.8 KB
  int tid = threadIdx.x;
  int lane = tid & 63;
  int wid = __builtin_amdgcn_readfirstlane(tid >> 6);
  int which = blockIdx.y;
  const float* X = (which == 0) ? q : (which == 1) ? k : v;
  const float* W = (which == 0) ? wq : (which == 1) ? wk : wv;
  int row0 = (blockIdx.x >> 2) * 32 + wid * 8;       // 64 row-tiles of 32
  int o0 = (blockIdx.x & 3) * 64;                    // 4 out-slices of 64
  float acc[8];
  gemm_selfstage(X, W, wlds, row0, o0, tid, lane, acc);
  int o = o0 + lane;
  int h = o >> 6, d = o & 63;
#pragma unroll
  for (int r = 0; r < 8; ++r) {
    int row = row0 + r;
    int b = row >> 9, t = row & 511;
    int bh = b * NH + h;
    float val = acc[r];
    if (which < 2) {
      // clamp +-5.5 (6.9 sigma; P(hit)~3e-6): quad product A0..A3 <= e^88 < fp32 max
      val = __expf(2.f * fminf(fmaxf(val, -5.5f), 5.5f));
    }
    if (which == 0) {
      EQ[((size_t)bh * TLEN + t) * DH + d] = val;
    } else if (which == 1) {
      EKT[(((size_t)bh * 16 + (d >> 2)) * SLEN + t) * 4 + (d & 3)] = val;
    } else {
      Vw[(size_t)bh * SLEN * DH + (size_t)(t >> 1) * 128 + d * 2 + (t & 1)] = val;
    }
  }
}

// ---- kernel B (byte-identical to R9): block = (bh, 4 t-rows); wave owns s-quarter.
//      grid 2048 -> 8 blocks/CU. Quad-combined rcp: 1 v_rcp per 4 d. ----
__global__ __launch_bounds__(256, 8) void attn_kernel(
    const float* __restrict__ EQ, const float* __restrict__ EKT,
    const float* __restrict__ Vw, const float* __restrict__ va_g,
    float* __restrict__ attn_out, float* __restrict__ attended) {
  __shared__ float pw[4][SLEN];      // probs, t-major
  __shared__ float fp[4][4][64];     // per-wave PV partials
  __shared__ float sred[4][4];       // cross-wave softmax sums
  int tid = threadIdx.x;
  int lane = tid & 63;
  int wid = __builtin_amdgcn_readfirstlane(tid >> 6);
  int bx = (int)((blockIdx.x & 7) * 256 + (blockIdx.x >> 3));  // bijective XCD swizzle (2048=8*256)
  int bh = bx >> 7;
  int tile = (bx & 127) * 4;
  int h = bh & 3, b = bh >> 2;
  int sq0 = wid * 128;               // this wave's s-quarter base

  const float4* ekf = (const float4*)EKT + (size_t)bh * (16 * SLEN) + sq0 + lane;
  const float* eqb = EQ + ((size_t)bh * TLEN + tile) * DH;   // uniform -> s_load
  const float* vap = va_g + h * DH;

  float acc[4][2];
#pragma unroll
  for (int t = 0; t < 4; ++t) { acc[t][0] = 0.f; acc[t][1] = 0.f; }
  float vsum = 0.f;

  float4 eA0, eA1, eB0, eB1;

#define LOADE(EV, dc_) do { EV##0 = ekf[(size_t)(dc_) * SLEN]; \
                            EV##1 = ekf[(size_t)(dc_) * SLEN + 64]; } while (0)

  // sum_{j=0..3} va_j/A_j = (n01*P23 + n23*P01) / (P01*P23): 14 VALU + 1 rcp
#define SC4(E, qv, av, aref) do {                                           \
    float A0 = fmaf(qv.x, E.x, 1.f), A1 = fmaf(qv.y, E.y, 1.f);             \
    float A2 = fmaf(qv.z, E.z, 1.f), A3 = fmaf(qv.w, E.w, 1.f);             \
    float n01 = fmaf(av.x, A1, av.y * A0);                                  \
    float n23 = fmaf(av.z, A3, av.w * A2);                                  \
    float P01 = A0 * A1, P23 = A2 * A3;                                     \
    float Nm = fmaf(n01, P23, n23 * P01);                                   \
    aref = fmaf(Nm, rcp_fast(P01 * P23), aref);                             \
  } while (0)

#define DCBODY(CUR, NXT, dc_) do {                                          \
    float4 av = *(const float4*)(vap + (dc_) * 4);                          \
    float4 q0 = *(const float4*)(eqb + 0 * DH + (dc_) * 4);                 \
    float4 q1 = *(const float4*)(eqb + 1 * DH + (dc_) * 4);                 \
    float4 q2 = *(const float4*)(eqb + 2 * DH + (dc_) * 4);                 \
    float4 q3 = *(const float4*)(eqb + 3 * DH + (dc_) * 4);                 \
    vsum += (av.x + av.y) + (av.z + av.w);                                  \
    if ((dc_) < 15) LOADE(NXT, (dc_) + 1);                                  \
    __builtin_amdgcn_sched_barrier(0);                                      \
    SC4(CUR##0, q0, av, acc[0][0]); SC4(CUR##1, q0, av, acc[0][1]);         \
    SC4(CUR##0, q1, av, acc[1][0]); SC4(CUR##1, q1, av, acc[1][1]);         \
    SC4(CUR##0, q2, av, acc[2][0]); SC4(CUR##1, q2, av, acc[2][1]);         \
    SC4(CUR##0, q3, av, acc[3][0]); SC4(CUR##1, q3, av, acc[3][1]);         \
  } while (0)

  LOADE(eA, 0);
#pragma unroll 1
  for (int dc2 = 0; dc2 < 8; ++dc2) {
    DCBODY(eA, eB, 2 * dc2);
    DCBODY(eB, eA, 2 * dc2 + 1);
  }

  // ---- softmax, no max-subtraction (|score| <= 0.125*sum|va| ~ 7, exp bounded) ----
  size_t bht = (size_t)bh * TLEN + tile;
  float e0[4], e1[4];
#pragma unroll
  for (int t = 0; t < 4; ++t) {
    float x0 = __expf(fmaf(acc[t][0], -0.25f, vsum * 0.125f));
    float x1 = __expf(fmaf(acc[t][1], -0.25f, vsum * 0.125f));
    e0[t] = x0; e1[t] = x1;
    float es = x0 + x1;
#pragma unroll
    for (int off = 32; off; off >>= 1) es += __shfl_xor(es, off);
    if (lane == 0) sred[t][wid] = es;
  }
  __syncthreads();
#pragma unroll
  for (int t = 0; t < 4; ++t) {
    float es = (sred[t][0] + sred[t][1]) + (sred[t][2] + sred[t][3]);
    float inv = rcp_fast(es);
    float p0 = e0[t] * inv, p1 = e1[t] * inv;
    pw[t][sq0 + lane] = p0;                 // own-wave region: no barrier needed
    pw[t][sq0 + 64 + lane] = p1;
    float* arow = attn_out + (bht + t) * SLEN + sq0;
    arow[lane] = p0;                        // coalesced 256B stores
    arow[64 + lane] = p1;
  }

  // ---- PV over own s-quarter: lane = d; probs via LDS broadcast (own writes) ----
  const float2* vb = (const float2*)Vw + (size_t)bh * (256 * 64) + (size_t)(wid * 64) * 64 + lane;
  float f[4];
#pragma unroll
  for (int t = 0; t < 4; ++t) f[t] = 0.f;
#pragma unroll 2
  for (int i = 0; i < 32; ++i) {            // s-quads within quarter
    float2 v01 = vb[(size_t)i * 128];       // coalesced b64: s-pair, d=lane
    float2 v23 = vb[(size_t)i * 128 + 64];
    int sb = sq0 + i * 4;
#pragma unroll
    for (int t = 0; t < 4; ++t) {
      float4 pq = *(const float4*)&pw[t][sb];   // uniform addr -> LDS broadcast
      f[t] = fmaf(pq.x, v01.x, f[t]);
      f[t] = fmaf(pq.y, v01.y, f[t]);
      f[t] = fmaf(pq.z, v23.x, f[t]);
      f[t] = fmaf(pq.w, v23.y, f[t]);
    }
  }
#pragma unroll
  for (int t = 0; t < 4; ++t) fp[wid][t][lane] = f[t];
  __syncthreads();
  {
    int t = wid;                            // wave reduces 1 t-row
    float s = (fp[0][t][lane] + fp[1][t][lane]) + (fp[2][t][lane] + fp[3][t][lane]);
    attended[((size_t)(b * TLEN) + tile + t) * DM + h * DH + lane] = s;
  }
}

// ---- kernel C: out = attended @ w_o.T, wo read directly (self-staged) ----
__global__ __launch_bounds__(256) void outproj_kernel(
    const float* __restrict__ att, const float* __restrict__ wo,
    float* __restrict__ out) {
  __shared__ float wlds[64 * WPAD];
  int tid = threadIdx.x;
  int lane = tid & 63;
  int wid = __builtin_amdgcn_readfirstlane(tid >> 6);
  int row0 = (blockIdx.x >> 2) * 32 + wid * 8;
  int o0 = (blockIdx.x & 3) * 64;
  float acc[8];
  gemm_selfstage(att, wo, wlds, row0, o0, tid, lane, acc);
  int o = o0 + lane;
#pragma unroll
  for (int r = 0; r < 8; ++r)
    out[(size_t)(row0 + r) * DM + o] = acc[r];      // coalesced b32
}

extern "C" void kernel_launch(void* const* d_in, const int* in_sizes, int n_in,
                              void* d_out, int out_size, void* d_ws, size_t ws_size,
                              hipStream_t stream) {
  const float* query = (const float*)d_in[0];
  const float* key   = (const float*)d_in[1];
  const float* value = (const float*)d_in[2];
  const float* wq    = (const float*)d_in[3];
  const float* wk    = (const float*)d_in[4];
  const float* wv    = (const float*)d_in[5];
  const float* va    = (const float*)d_in[6];
  const float* wo    = (const float*)d_in[7];

  float* out  = (float*)d_out;                 // (B,T,DM)
  float* attn = out + (size_t)BT * DM;         // (B,H,T,S)

  const size_t SEG = (size_t)BT * DM;          // 524288 floats = 2MB
  float* EQ  = (float*)d_ws;                   // [bh][t][d]
  float* EKT = EQ + SEG;                       // [bh][dc16][s][j4]
  float* Vw  = EKT + SEG;                      // [bh][s/2][d][2]
  float* att = Vw + SEG;                       // attended [b][t][h*64+d]

  proj_kernel<<<dim3(256, 3), 256, 0, stream>>>(query, key, value, wq, wk, wv, EQ, EKT, Vw);
  attn_kernel<<<dim3(2048), 256, 0, stream>>>(EQ, EKT, Vw, va, attn, att);
  outproj_kernel<<<dim3(256), 256, 0, stream>>>(att, wo, out);
}